// Round 7
// baseline (236.344 us; speedup 1.0000x reference)
//
#include <hip/hip_runtime.h>
#include <math.h>

#define DD 128          // embed dim
#define DEG 16          // neighbors
#define TMR 8           // real node rows per block (grid = 50000/8 = 6250)
#define TMP 16          // padded rows for the 16x16 MFMA (rows 8..15 zero)
#define LDST 136        // LDS row stride in f16
#define EPSV 1e-5f

typedef _Float16 half4_t __attribute__((ext_vector_type(4)));
typedef _Float16 half8_t __attribute__((ext_vector_type(8)));
typedef float    f32x4   __attribute__((ext_vector_type(4)));

// ---- prep (single kernel): x16[s] = x[s]*mask[s]^2 (f16), plus W->f16 transpose.
// Folding mask^2 removes all mask gathers: msg[s] = m_s*((m_s*x[s])@W) = (m_s^2*x[s])@W.
__global__ void prep(const float* __restrict__ x, const float* __restrict__ mask,
                     _Float16* __restrict__ x16, int n4, int xb,
                     const float* __restrict__ Wp, const float* __restrict__ Wn,
                     _Float16* __restrict__ WT)
{
    if ((int)blockIdx.x < xb) {
        int i = blockIdx.x * blockDim.x + threadIdx.x;
        if (i >= n4) return;
        float m = mask[i >> 5];            // 32 half4 groups per row
        float m2 = m * m;
        float4 v = ((const float4*)x)[i];
        half4_t h;
        h[0] = (_Float16)(v.x * m2); h[1] = (_Float16)(v.y * m2);
        h[2] = (_Float16)(v.z * m2); h[3] = (_Float16)(v.w * m2);
        ((half4_t*)x16)[i] = h;
    } else {
        // 32 blocks: mat = (l,rel) in WT order [l0p, l0n, l1p, l1n], 8 chunks each
        int bid   = blockIdx.x - xb;
        int mat   = bid >> 3;              // 0..3
        int chunk = bid & 7;
        int l = mat >> 1, rel = mat & 1;
        const float* __restrict__ src = (rel ? Wn : Wp) + (size_t)l * DD * DD;
        _Float16* __restrict__ dst = WT + (size_t)mat * DD * DD;
        for (int o = chunk * 2048 + threadIdx.x; o < chunk * 2048 + 2048; o += 256) {
            int nn = o >> 7, kk = o & 127;
            dst[o] = (_Float16)src[kk * DD + nn];   // WT[n][k] (transposed)
        }
    }
}

// ---- one fused GNN layer ----
__global__ __launch_bounds__(256, 6) void fused_layer(
    const _Float16* __restrict__ src16,          // pre-scaled by mask^2
    const int*   __restrict__ adj, const float* __restrict__ wgt,
    const float* __restrict__ mask,
    const _Float16* __restrict__ WTp, const _Float16* __restrict__ WTn,
    float* __restrict__ dst_f32, _Float16* __restrict__ dst_f16,
    int n, int apply_logmap)
{
    __shared__ __align__(16) _Float16 aggP[TMP][LDST];   // 4.25 KB
    __shared__ __align__(16) _Float16 aggN[TMP][LDST];   // 4.25 KB
    __shared__ float partA[4][TMP];                       // cross-wave norm partials
    __shared__ float partB[4][TMP];

    const int row0   = blockIdx.x * TMR;
    const int tid    = threadIdx.x;
    const int hw     = tid >> 5;       // half-wave 0..7 -> owns node row hw
    const int lane32 = tid & 31;       // covers cols [4*lane32, 4*lane32+4)

    // ---- phase 1: gather-aggregate; ALL 16 edges in flight, 8B/lane loads
    //      (2 random 256B rows per wave-inst — the best shape per R4/R5/R6) ----
    float aP[4] = {0.f, 0.f, 0.f, 0.f};
    float aN[4] = {0.f, 0.f, 0.f, 0.f};
    const int node = row0 + hw;
    if (node < n) {
        const int*   __restrict__ arow = adj + (size_t)node * DEG;
        const float* __restrict__ wrow = wgt + (size_t)node * DEG;
        int4   ia0 = ((const int4*)arow)[0];
        int4   ia1 = ((const int4*)arow)[1];
        int4   ia2 = ((const int4*)arow)[2];
        int4   ia3 = ((const int4*)arow)[3];
        float4 wa0 = ((const float4*)wrow)[0];
        float4 wa1 = ((const float4*)wrow)[1];
        float4 wa2 = ((const float4*)wrow)[2];
        float4 wa3 = ((const float4*)wrow)[3];
        const int idxs[16] = {ia0.x, ia0.y, ia0.z, ia0.w, ia1.x, ia1.y, ia1.z, ia1.w,
                              ia2.x, ia2.y, ia2.z, ia2.w, ia3.x, ia3.y, ia3.z, ia3.w};
        const float ws[16] = {wa0.x, wa0.y, wa0.z, wa0.w, wa1.x, wa1.y, wa1.z, wa1.w,
                              wa2.x, wa2.y, wa2.z, wa2.w, wa3.x, wa3.y, wa3.z, wa3.w};
        half4_t v[16];                  // 16 independent 8B gathers in flight
        #pragma unroll
        for (int j = 0; j < 16; ++j)
            v[j] = *(const half4_t*)(src16 + (size_t)idxs[j] * DD + lane32 * 4);
        #pragma unroll
        for (int j = 0; j < 16; ++j) {
            float wp = fmaxf(ws[j], 0.f);
            float wn = fmaxf(-ws[j], 0.f);
            #pragma unroll
            for (int c = 0; c < 4; ++c) {
                float f = (float)v[j][c];
                aP[c] += wp * f;
                aN[c] += wn * f;
            }
        }
    }
    half4_t hP, hN, hz;
    #pragma unroll
    for (int c = 0; c < 4; ++c) {
        hP[c] = (_Float16)aP[c]; hN[c] = (_Float16)aN[c]; hz[c] = (_Float16)0.f;
    }
    *(half4_t*)&aggP[hw][lane32 * 4] = hP;
    *(half4_t*)&aggN[hw][lane32 * 4] = hN;
    *(half4_t*)&aggP[TMR + hw][lane32 * 4] = hz;   // zero pad rows 8..15
    *(half4_t*)&aggN[TMR + hw][lane32 * 4] = hz;
    __syncthreads();

    // ---- phase 2: MFMA. 4 waves split the 8 n-blocks (2 each); rows shared ----
    const int wv2  = tid >> 6;       // wave 0..3
    const int l64  = tid & 63;
    const int l15  = l64 & 15;
    const int quad = l64 >> 4;

    half8_t aPf[4], aNf[4];          // A[m=l15][k=kb*32+quad*8+j]
    #pragma unroll
    for (int kb = 0; kb < 4; ++kb) {
        aPf[kb] = *(const half8_t*)&aggP[l15][kb * 32 + quad * 8];
        aNf[kb] = *(const half8_t*)&aggN[l15][kb * 32 + quad * 8];
    }

    f32x4 acc[2];
    acc[0] = (f32x4){0.f, 0.f, 0.f, 0.f};
    acc[1] = (f32x4){0.f, 0.f, 0.f, 0.f};
    #pragma unroll
    for (int t = 0; t < 2; ++t) {
        const int nb = wv2 * 2 + t;
        const _Float16* bp = WTp + (size_t)(nb * 16 + l15) * DD + quad * 8;
        const _Float16* bn = WTn + (size_t)(nb * 16 + l15) * DD + quad * 8;
        #pragma unroll
        for (int kb = 0; kb < 4; ++kb) {
            acc[t] = __builtin_amdgcn_mfma_f32_16x16x32_f16(
                aPf[kb], *(const half8_t*)(bp + kb * 32), acc[t], 0, 0, 0);
            acc[t] = __builtin_amdgcn_mfma_f32_16x16x32_f16(
                aNf[kb], *(const half8_t*)(bn + kb * 32), acc[t], 0, 0, 0);
        }
    }

    // ---- phase 3: epilogue. C/D: row=quad*4+r, cols wv2*32 + {l15, 16+l15} ----
    float cv0[4], cv1[4], mr[4];
    #pragma unroll
    for (int r = 0; r < 4; ++r) {
        const int rl  = quad * 4 + r;
        const int row = row0 + rl;
        float m = (rl < TMR && row < n) ? mask[row] : 0.f;
        mr[r] = m;
        float c0 = acc[0][r] * m, c1 = acc[1][r] * m;
        cv0[r] = c0; cv1[r] = c1;
        float p = c0 * c0 + c1 * c1;
        p += __shfl_xor(p, 1); p += __shfl_xor(p, 2);
        p += __shfl_xor(p, 4); p += __shfl_xor(p, 8);   // within 16-lane group
        if (l15 == 0) partA[wv2][rl] = p;
    }
    __syncthreads();

    float x0[4], x1[4];
    #pragma unroll
    for (int r = 0; r < 4; ++r) {
        const int rl = quad * 4 + r;
        float c2 = partA[0][rl] + partA[1][rl] + partA[2][rl] + partA[3][rl];
        float nc = fmaxf(sqrtf(c2), EPSV);
        float sc = tanhf(nc) / nc;
        float m  = mr[r];
        float t0 = fmaxf(cv0[r] * sc * m, 0.f) * m;      // expmap*m, relu, *m
        float t1 = fmaxf(cv1[r] * sc * m, 0.f) * m;
        x0[r] = t0; x1[r] = t1;
        if (apply_logmap) {                               // uniform branch
            float p = t0 * t0 + t1 * t1;
            p += __shfl_xor(p, 1); p += __shfl_xor(p, 2);
            p += __shfl_xor(p, 4); p += __shfl_xor(p, 8);
            if (l15 == 0) partB[wv2][rl] = p;
        }
    }

    if (apply_logmap) {
        __syncthreads();
        #pragma unroll
        for (int r = 0; r < 4; ++r) {
            const int rl  = quad * 4 + r;
            const int row = row0 + rl;
            if (rl >= TMR || row >= n) continue;
            float s2  = partB[0][rl] + partB[1][rl] + partB[2][rl] + partB[3][rl];
            float nc2 = fminf(fmaxf(sqrtf(s2), EPSV), 1.f - EPSV);
            // store logmap(x)*mask^2 so the next layer's gather needs no mask
            float f = (atanhf(nc2) / nc2) * mr[r] * mr[r];
            _Float16* drow = dst_f16 + (size_t)row * DD + wv2 * 32 + l15;
            drow[0]  = (_Float16)(x0[r] * f);
            drow[16] = (_Float16)(x1[r] * f);
        }
    } else {
        #pragma unroll
        for (int r = 0; r < 4; ++r) {
            const int rl  = quad * 4 + r;
            const int row = row0 + rl;
            if (rl >= TMR || row >= n) continue;
            float* drow = dst_f32 + (size_t)row * DD + wv2 * 32 + l15;
            drow[0]  = x0[r];
            drow[16] = x1[r];
        }
    }
}

extern "C" void kernel_launch(void* const* d_in, const int* in_sizes, int n_in,
                              void* d_out, int out_size, void* d_ws, size_t ws_size,
                              hipStream_t stream)
{
    const float* node_repr = (const float*)d_in[0];
    const int*   adj       = (const int*)  d_in[1];
    const float* weight    = (const float*)d_in[2];
    const float* mask      = (const float*)d_in[3];
    const float* W_pos     = (const float*)d_in[4];   // [L,128,128]
    const float* W_neg     = (const float*)d_in[5];

    const int n = in_sizes[0] / DD;                   // 50000

    _Float16* x16 = (_Float16*)d_ws;                  // n*128 f16
    _Float16* y16 = x16 + (size_t)n * DD;             // n*128 f16
    _Float16* WT  = y16 + (size_t)n * DD;             // 4 * 128*128 f16

    const int n4 = n * DD / 4;
    const int xb = (n4 + 255) / 256;
    prep<<<xb + 32, 256, 0, stream>>>(node_repr, mask, x16, n4, xb,
                                      W_pos, W_neg, WT);

    dim3 grid((n + TMR - 1) / TMR);
    // layer 0
    fused_layer<<<grid, 256, 0, stream>>>(x16, adj, weight, mask,
                                          WT + 0 * DD * DD, WT + 1 * DD * DD,
                                          nullptr, y16, n, 1);
    // layer 1
    fused_layer<<<grid, 256, 0, stream>>>(y16, adj, weight, mask,
                                          WT + 2 * DD * DD, WT + 3 * DD * DD,
                                          (float*)d_out, nullptr, n, 0);
}

// Round 8
// 210.089 us; speedup vs baseline: 1.1250x; 1.1250x over previous
//
#include <hip/hip_runtime.h>
#include <math.h>

#define DD 128          // embed dim
#define DEG 16          // neighbors
#define NPW 16          // nodes per wave (one full MFMA M-tile per wave)
#define LDST 136        // LDS row stride in f16
#define EPSV 1e-5f

typedef _Float16 half4_t __attribute__((ext_vector_type(4)));
typedef _Float16 half8_t __attribute__((ext_vector_type(8)));
typedef float    f32x4   __attribute__((ext_vector_type(4)));

// ---- prep (single kernel): x16[s] = x[s]*mask[s]^2 (f16), plus W->f16 transpose.
// Folding mask^2 removes all mask gathers: msg[s] = m_s*((m_s*x[s])@W) = (m_s^2*x[s])@W.
__global__ void prep(const float* __restrict__ x, const float* __restrict__ mask,
                     _Float16* __restrict__ x16, int n4, int xb,
                     const float* __restrict__ Wp, const float* __restrict__ Wn,
                     _Float16* __restrict__ WT)
{
    if ((int)blockIdx.x < xb) {
        int i = blockIdx.x * blockDim.x + threadIdx.x;
        if (i >= n4) return;
        float m = mask[i >> 5];            // 32 half4 groups per row
        float m2 = m * m;
        float4 v = ((const float4*)x)[i];
        half4_t h;
        h[0] = (_Float16)(v.x * m2); h[1] = (_Float16)(v.y * m2);
        h[2] = (_Float16)(v.z * m2); h[3] = (_Float16)(v.w * m2);
        ((half4_t*)x16)[i] = h;
    } else {
        // 32 blocks: mat = (l,rel) in WT order [l0p, l0n, l1p, l1n], 8 chunks each
        int bid   = blockIdx.x - xb;
        int mat   = bid >> 3;              // 0..3
        int chunk = bid & 7;
        int l = mat >> 1, rel = mat & 1;
        const float* __restrict__ src = (rel ? Wn : Wp) + (size_t)l * DD * DD;
        _Float16* __restrict__ dst = WT + (size_t)mat * DD * DD;
        for (int o = chunk * 2048 + threadIdx.x; o < chunk * 2048 + 2048; o += 256) {
            int nn = o >> 7, kk = o & 127;
            dst[o] = (_Float16)src[kk * DD + nn];   // WT[n][k] (transposed)
        }
    }
}

// ---- one fused GNN layer; BARRIER-FREE: each wave is fully autonomous ----
__global__ __launch_bounds__(256, 4) void fused_layer(
    const _Float16* __restrict__ src16,          // pre-scaled by mask^2
    const int*   __restrict__ adj, const float* __restrict__ wgt,
    const float* __restrict__ mask,
    const _Float16* __restrict__ WTp, const _Float16* __restrict__ WTn,
    float* __restrict__ dst_f32, _Float16* __restrict__ dst_f16,
    int n, int apply_logmap)
{
    // wave-private LDS slices — no cross-wave sharing, no __syncthreads
    __shared__ __align__(16) _Float16 aggP[4][NPW][LDST];   // 17.4 KB
    __shared__ __align__(16) _Float16 aggN[4][NPW][LDST];   // 17.4 KB

    const int tid    = threadIdx.x;
    const int wv     = tid >> 6;       // wave 0..3 in block
    const int l64    = tid & 63;
    const int hw     = l64 >> 5;       // half-wave 0/1 within the wave
    const int lane32 = l64 & 31;       // covers cols [4*lane32, 4*lane32+4)

    const int wave_id = blockIdx.x * 4 + wv;
    const int row0    = wave_id * NPW;
    if (row0 >= n) return;             // wave-uniform exit (no barriers below)

    _Float16 (* __restrict__ aP_lds)[LDST] = aggP[wv];
    _Float16 (* __restrict__ aN_lds)[LDST] = aggN[wv];

    // ---- phase 1: gather-aggregate; 8 nodes per half-wave, each node's 16
    //      edges fully in flight as 8B/lane loads (2 random rows per inst) ----
    for (int i = 0; i < 8; ++i) {
        const int r    = hw * 8 + i;
        const int node = row0 + r;
        float aP[4] = {0.f, 0.f, 0.f, 0.f};
        float aN[4] = {0.f, 0.f, 0.f, 0.f};
        if (node < n) {
            const int*   __restrict__ arow = adj + (size_t)node * DEG;
            const float* __restrict__ wrow = wgt + (size_t)node * DEG;
            int4   ia0 = ((const int4*)arow)[0];
            int4   ia1 = ((const int4*)arow)[1];
            int4   ia2 = ((const int4*)arow)[2];
            int4   ia3 = ((const int4*)arow)[3];
            float4 wa0 = ((const float4*)wrow)[0];
            float4 wa1 = ((const float4*)wrow)[1];
            float4 wa2 = ((const float4*)wrow)[2];
            float4 wa3 = ((const float4*)wrow)[3];
            const int idxs[16] = {ia0.x, ia0.y, ia0.z, ia0.w, ia1.x, ia1.y, ia1.z, ia1.w,
                                  ia2.x, ia2.y, ia2.z, ia2.w, ia3.x, ia3.y, ia3.z, ia3.w};
            const float ws[16] = {wa0.x, wa0.y, wa0.z, wa0.w, wa1.x, wa1.y, wa1.z, wa1.w,
                                  wa2.x, wa2.y, wa2.z, wa2.w, wa3.x, wa3.y, wa3.z, wa3.w};
            half4_t v[16];              // 16 independent 8B gathers in flight
            #pragma unroll
            for (int j = 0; j < 16; ++j)
                v[j] = *(const half4_t*)(src16 + (size_t)idxs[j] * DD + lane32 * 4);
            #pragma unroll
            for (int j = 0; j < 16; ++j) {
                float wp = fmaxf(ws[j], 0.f);
                float wn = fmaxf(-ws[j], 0.f);
                #pragma unroll
                for (int c = 0; c < 4; ++c) {
                    float f = (float)v[j][c];
                    aP[c] += wp * f;
                    aN[c] += wn * f;
                }
            }
        }
        half4_t hP, hN;
        #pragma unroll
        for (int c = 0; c < 4; ++c) { hP[c] = (_Float16)aP[c]; hN[c] = (_Float16)aN[c]; }
        *(half4_t*)&aP_lds[r][lane32 * 4] = hP;
        *(half4_t*)&aN_lds[r][lane32 * 4] = hN;
    }
    __threadfence_block();   // order this wave's LDS writes before its reads

    // ---- phase 2: full 16x128 MFMA for this wave's 16 rows ----
    const int l15  = l64 & 15;
    const int quad = l64 >> 4;

    half8_t aPf[4], aNf[4];          // A[m=l15][k=kb*32+quad*8+j]
    #pragma unroll
    for (int kb = 0; kb < 4; ++kb) {
        aPf[kb] = *(const half8_t*)&aP_lds[l15][kb * 32 + quad * 8];
        aNf[kb] = *(const half8_t*)&aN_lds[l15][kb * 32 + quad * 8];
    }

    f32x4 acc[8];
    #pragma unroll
    for (int nb = 0; nb < 8; ++nb) acc[nb] = (f32x4){0.f, 0.f, 0.f, 0.f};
    #pragma unroll
    for (int nb = 0; nb < 8; ++nb) {
        const _Float16* bp = WTp + (size_t)(nb * 16 + l15) * DD + quad * 8;
        const _Float16* bn = WTn + (size_t)(nb * 16 + l15) * DD + quad * 8;
        #pragma unroll
        for (int kb = 0; kb < 4; ++kb) {
            acc[nb] = __builtin_amdgcn_mfma_f32_16x16x32_f16(
                aPf[kb], *(const half8_t*)(bp + kb * 32), acc[nb], 0, 0, 0);
            acc[nb] = __builtin_amdgcn_mfma_f32_16x16x32_f16(
                aNf[kb], *(const half8_t*)(bn + kb * 32), acc[nb], 0, 0, 0);
        }
    }

    // ---- phase 3: epilogue. C/D: row=quad*4+r, col=nb*16+l15.
    //      Full row norm = shuffle over the 16-lane l15 group (all 8 nb local) ----
    #pragma unroll
    for (int r = 0; r < 4; ++r) {
        const int rl  = quad * 4 + r;
        const int row = row0 + rl;
        const float m = (row < n) ? mask[row] : 0.f;

        float cv[8];
        float c2 = 0.f;
        #pragma unroll
        for (int nb = 0; nb < 8; ++nb) { cv[nb] = acc[nb][r] * m; c2 += cv[nb] * cv[nb]; }
        c2 += __shfl_xor(c2, 1); c2 += __shfl_xor(c2, 2);
        c2 += __shfl_xor(c2, 4); c2 += __shfl_xor(c2, 8);
        float nc = fmaxf(sqrtf(c2), EPSV);
        float sc = tanhf(nc) / nc;

        float xv[8];
        float s2 = 0.f;
        #pragma unroll
        for (int nb = 0; nb < 8; ++nb) {
            float t = fmaxf(cv[nb] * sc * m, 0.f) * m;   // expmap*m, relu, *m
            xv[nb] = t; s2 += t * t;
        }

        if (apply_logmap) {                               // uniform branch
            s2 += __shfl_xor(s2, 1); s2 += __shfl_xor(s2, 2);
            s2 += __shfl_xor(s2, 4); s2 += __shfl_xor(s2, 8);
            float nc2 = fminf(fmaxf(sqrtf(s2), EPSV), 1.f - EPSV);
            // store logmap(x)*mask^2 so the next layer's gather needs no mask
            float f = (atanhf(nc2) / nc2) * m * m;
            if (row < n) {
                _Float16* drow = dst_f16 + (size_t)row * DD + l15;
                #pragma unroll
                for (int nb = 0; nb < 8; ++nb) drow[nb * 16] = (_Float16)(xv[nb] * f);
            }
        } else {
            if (row < n) {
                float* drow = dst_f32 + (size_t)row * DD + l15;
                #pragma unroll
                for (int nb = 0; nb < 8; ++nb) drow[nb * 16] = xv[nb];
            }
        }
    }
}

extern "C" void kernel_launch(void* const* d_in, const int* in_sizes, int n_in,
                              void* d_out, int out_size, void* d_ws, size_t ws_size,
                              hipStream_t stream)
{
    const float* node_repr = (const float*)d_in[0];
    const int*   adj       = (const int*)  d_in[1];
    const float* weight    = (const float*)d_in[2];
    const float* mask      = (const float*)d_in[3];
    const float* W_pos     = (const float*)d_in[4];   // [L,128,128]
    const float* W_neg     = (const float*)d_in[5];

    const int n = in_sizes[0] / DD;                   // 50000

    _Float16* x16 = (_Float16*)d_ws;                  // n*128 f16
    _Float16* y16 = x16 + (size_t)n * DD;             // n*128 f16
    _Float16* WT  = y16 + (size_t)n * DD;             // 4 * 128*128 f16

    const int n4 = n * DD / 4;
    const int xb = (n4 + 255) / 256;
    prep<<<xb + 32, 256, 0, stream>>>(node_repr, mask, x16, n4, xb,
                                      W_pos, W_neg, WT);

    const int waves = (n + NPW - 1) / NPW;            // 3125
    dim3 grid((waves + 3) / 4);                       // 782 blocks x 4 waves
    // layer 0
    fused_layer<<<grid, 256, 0, stream>>>(x16, adj, weight, mask,
                                          WT + 0 * DD * DD, WT + 1 * DD * DD,
                                          nullptr, y16, n, 1);
    // layer 1
    fused_layer<<<grid, 256, 0, stream>>>(y16, adj, weight, mask,
                                          WT + 2 * DD * DD, WT + 3 * DD * DD,
                                          (float*)d_out, nullptr, n, 0);
}

// Round 9
// 199.956 us; speedup vs baseline: 1.1820x; 1.0507x over previous
//
#include <hip/hip_runtime.h>
#include <math.h>

#define DD 128          // embed dim
#define DEG 16          // neighbors
#define NPW 16          // nodes per wave (one full MFMA M-tile per wave)
#define LDST 136        // LDS row stride in f16
#define EPSV 1e-5f

typedef _Float16 half4_t __attribute__((ext_vector_type(4)));
typedef _Float16 half8_t __attribute__((ext_vector_type(8)));
typedef float    f32x4   __attribute__((ext_vector_type(4)));

__device__ __forceinline__ int4 shfl4i(int4 v, int src) {
    int4 r;
    r.x = __shfl(v.x, src, 32); r.y = __shfl(v.y, src, 32);
    r.z = __shfl(v.z, src, 32); r.w = __shfl(v.w, src, 32);
    return r;
}
__device__ __forceinline__ float4 shfl4f(float4 v, int src) {
    float4 r;
    r.x = __shfl(v.x, src, 32); r.y = __shfl(v.y, src, 32);
    r.z = __shfl(v.z, src, 32); r.w = __shfl(v.w, src, 32);
    return r;
}

// ---- prep (single kernel): x16[s] = x[s]*mask[s]^2 (f16), plus W->f16 transpose.
// Folding mask^2 removes all mask gathers: msg[s] = m_s*((m_s*x[s])@W) = (m_s^2*x[s])@W.
__global__ void prep(const float* __restrict__ x, const float* __restrict__ mask,
                     _Float16* __restrict__ x16, int n4, int xb,
                     const float* __restrict__ Wp, const float* __restrict__ Wn,
                     _Float16* __restrict__ WT)
{
    if ((int)blockIdx.x < xb) {
        int i = blockIdx.x * blockDim.x + threadIdx.x;
        if (i >= n4) return;
        float m = mask[i >> 5];            // 32 half4 groups per row
        float m2 = m * m;
        float4 v = ((const float4*)x)[i];
        half4_t h;
        h[0] = (_Float16)(v.x * m2); h[1] = (_Float16)(v.y * m2);
        h[2] = (_Float16)(v.z * m2); h[3] = (_Float16)(v.w * m2);
        ((half4_t*)x16)[i] = h;
    } else {
        int bid   = blockIdx.x - xb;
        int mat   = bid >> 3;              // 0..3: [l0p, l0n, l1p, l1n]
        int chunk = bid & 7;
        int l = mat >> 1, rel = mat & 1;
        const float* __restrict__ src = (rel ? Wn : Wp) + (size_t)l * DD * DD;
        _Float16* __restrict__ dst = WT + (size_t)mat * DD * DD;
        for (int o = chunk * 2048 + threadIdx.x; o < chunk * 2048 + 2048; o += 256) {
            int nn = o >> 7, kk = o & 127;
            dst[o] = (_Float16)src[kk * DD + nn];   // WT[n][k] (transposed)
        }
    }
}

// ---- one fused GNN layer; barrier-free waves + software-pipelined gathers ----
__global__ __launch_bounds__(256, 3) void fused_layer(
    const _Float16* __restrict__ src16,          // pre-scaled by mask^2
    const int*   __restrict__ adj, const float* __restrict__ wgt,
    const float* __restrict__ mask,
    const _Float16* __restrict__ WTp, const _Float16* __restrict__ WTn,
    float* __restrict__ dst_f32, _Float16* __restrict__ dst_f16,
    int n, int apply_logmap)
{
    // wave-private LDS slices — no cross-wave sharing, no __syncthreads
    __shared__ __align__(16) _Float16 aggP[4][NPW][LDST];   // 17.4 KB
    __shared__ __align__(16) _Float16 aggN[4][NPW][LDST];   // 17.4 KB

    const int tid    = threadIdx.x;
    const int wv     = tid >> 6;       // wave 0..3 in block
    const int l64    = tid & 63;
    const int hw     = l64 >> 5;       // half-wave 0/1 within the wave
    const int lane32 = l64 & 31;       // covers cols [4*lane32, 4*lane32+4)

    const int wave_id = blockIdx.x * 4 + wv;
    const int row0    = wave_id * NPW;
    if (row0 >= n) return;             // wave-uniform exit (no barriers below)

    _Float16 (* __restrict__ aP_lds)[LDST] = aggP[wv];
    _Float16 (* __restrict__ aN_lds)[LDST] = aggN[wv];

    // ---- metadata upfront, DISTRIBUTED across lanes (2 vmem insts total):
    //      lane l holds edges 4l..4l+3 of this half-wave's 8-node strip ----
    const int hrow0 = row0 + hw * 8;            // first node of this half-wave
    // strip is 8 nodes x 16 edges = 128 ints; lane l -> int4 #l  (n%16==0 path)
    int4   mi = ((const int4*)  (adj + (size_t)hrow0 * DEG))[lane32];
    float4 mw = ((const float4*)(wgt + (size_t)hrow0 * DEG))[lane32];

    // issue node i's 16 gathers (idx via shfl broadcast; no in-loop vmem deps)
    auto issue = [&](int i, half4_t* v) {
        int4 a0 = shfl4i(mi, 4 * i + 0);
        int4 a1 = shfl4i(mi, 4 * i + 1);
        int4 a2 = shfl4i(mi, 4 * i + 2);
        int4 a3 = shfl4i(mi, 4 * i + 3);
        const int id[16] = {a0.x, a0.y, a0.z, a0.w, a1.x, a1.y, a1.z, a1.w,
                            a2.x, a2.y, a2.z, a2.w, a3.x, a3.y, a3.z, a3.w};
        #pragma unroll
        for (int j = 0; j < 16; ++j)
            v[j] = *(const half4_t*)(src16 + (size_t)id[j] * DD + lane32 * 4);
    };
    // accumulate node i from its gathered buffer, write agg row to LDS
    auto accum = [&](int i, half4_t* v) {
        float4 w0 = shfl4f(mw, 4 * i + 0);
        float4 w1 = shfl4f(mw, 4 * i + 1);
        float4 w2 = shfl4f(mw, 4 * i + 2);
        float4 w3 = shfl4f(mw, 4 * i + 3);
        const float ww[16] = {w0.x, w0.y, w0.z, w0.w, w1.x, w1.y, w1.z, w1.w,
                              w2.x, w2.y, w2.z, w2.w, w3.x, w3.y, w3.z, w3.w};
        float aP[4] = {0.f, 0.f, 0.f, 0.f};
        float aN[4] = {0.f, 0.f, 0.f, 0.f};
        #pragma unroll
        for (int j = 0; j < 16; ++j) {
            float wp = fmaxf(ww[j], 0.f);
            float wn = fmaxf(-ww[j], 0.f);
            #pragma unroll
            for (int c = 0; c < 4; ++c) {
                float f = (float)v[j][c];
                aP[c] += wp * f;
                aN[c] += wn * f;
            }
        }
        const int r = hw * 8 + i;
        half4_t hP, hN;
        #pragma unroll
        for (int c = 0; c < 4; ++c) { hP[c] = (_Float16)aP[c]; hN[c] = (_Float16)aN[c]; }
        *(half4_t*)&aP_lds[r][lane32 * 4] = hP;
        *(half4_t*)&aN_lds[r][lane32 * 4] = hN;
    };

    // ---- phase 1: double-buffered pipeline; 16 gathers stay in flight
    //      during every accumulate (compiler emits s_waitcnt vmcnt(16)) ----
    half4_t va[16], vb[16];
    issue(0, va);
    #pragma unroll
    for (int i = 0; i < 8; i += 2) {
        if (i + 1 < 8) issue(i + 1, vb);
        accum(i, va);
        if (i + 2 < 8) issue(i + 2, va);
        accum(i + 1, vb);
    }
    __threadfence_block();   // order this wave's LDS writes before its reads

    // ---- phase 2: full 16x128 MFMA for this wave's 16 rows ----
    const int l15  = l64 & 15;
    const int quad = l64 >> 4;

    half8_t aPf[4], aNf[4];          // A[m=l15][k=kb*32+quad*8+j]
    #pragma unroll
    for (int kb = 0; kb < 4; ++kb) {
        aPf[kb] = *(const half8_t*)&aP_lds[l15][kb * 32 + quad * 8];
        aNf[kb] = *(const half8_t*)&aN_lds[l15][kb * 32 + quad * 8];
    }

    f32x4 acc[8];
    #pragma unroll
    for (int nb = 0; nb < 8; ++nb) acc[nb] = (f32x4){0.f, 0.f, 0.f, 0.f};
    #pragma unroll
    for (int nb = 0; nb < 8; ++nb) {
        const _Float16* bp = WTp + (size_t)(nb * 16 + l15) * DD + quad * 8;
        const _Float16* bn = WTn + (size_t)(nb * 16 + l15) * DD + quad * 8;
        #pragma unroll
        for (int kb = 0; kb < 4; ++kb) {
            acc[nb] = __builtin_amdgcn_mfma_f32_16x16x32_f16(
                aPf[kb], *(const half8_t*)(bp + kb * 32), acc[nb], 0, 0, 0);
            acc[nb] = __builtin_amdgcn_mfma_f32_16x16x32_f16(
                aNf[kb], *(const half8_t*)(bn + kb * 32), acc[nb], 0, 0, 0);
        }
    }

    // ---- phase 3: epilogue. C/D: row=quad*4+r, col=nb*16+l15.
    //      Full row norm = shuffle over the 16-lane l15 group ----
    #pragma unroll
    for (int r = 0; r < 4; ++r) {
        const int rl  = quad * 4 + r;
        const int row = row0 + rl;
        const float m = (row < n) ? mask[row] : 0.f;

        float cv[8];
        float c2 = 0.f;
        #pragma unroll
        for (int nb = 0; nb < 8; ++nb) { cv[nb] = acc[nb][r] * m; c2 += cv[nb] * cv[nb]; }
        c2 += __shfl_xor(c2, 1); c2 += __shfl_xor(c2, 2);
        c2 += __shfl_xor(c2, 4); c2 += __shfl_xor(c2, 8);
        float nc = fmaxf(sqrtf(c2), EPSV);
        float sc = tanhf(nc) / nc;

        float xv[8];
        float s2 = 0.f;
        #pragma unroll
        for (int nb = 0; nb < 8; ++nb) {
            float t = fmaxf(cv[nb] * sc * m, 0.f) * m;   // expmap*m, relu, *m
            xv[nb] = t; s2 += t * t;
        }

        if (apply_logmap) {                               // uniform branch
            s2 += __shfl_xor(s2, 1); s2 += __shfl_xor(s2, 2);
            s2 += __shfl_xor(s2, 4); s2 += __shfl_xor(s2, 8);
            float nc2 = fminf(fmaxf(sqrtf(s2), EPSV), 1.f - EPSV);
            // store logmap(x)*mask^2 so the next layer's gather needs no mask
            float f = (atanhf(nc2) / nc2) * m * m;
            if (row < n) {
                _Float16* drow = dst_f16 + (size_t)row * DD + l15;
                #pragma unroll
                for (int nb = 0; nb < 8; ++nb) drow[nb * 16] = (_Float16)(xv[nb] * f);
            }
        } else {
            if (row < n) {
                float* drow = dst_f32 + (size_t)row * DD + l15;
                #pragma unroll
                for (int nb = 0; nb < 8; ++nb) drow[nb * 16] = xv[nb];
            }
        }
    }
}

extern "C" void kernel_launch(void* const* d_in, const int* in_sizes, int n_in,
                              void* d_out, int out_size, void* d_ws, size_t ws_size,
                              hipStream_t stream)
{
    const float* node_repr = (const float*)d_in[0];
    const int*   adj       = (const int*)  d_in[1];
    const float* weight    = (const float*)d_in[2];
    const float* mask      = (const float*)d_in[3];
    const float* W_pos     = (const float*)d_in[4];   // [L,128,128]
    const float* W_neg     = (const float*)d_in[5];

    const int n = in_sizes[0] / DD;                   // 50000 (divisible by NPW)

    _Float16* x16 = (_Float16*)d_ws;                  // n*128 f16
    _Float16* y16 = x16 + (size_t)n * DD;             // n*128 f16
    _Float16* WT  = y16 + (size_t)n * DD;             // 4 * 128*128 f16

    const int n4 = n * DD / 4;
    const int xb = (n4 + 255) / 256;
    prep<<<xb + 32, 256, 0, stream>>>(node_repr, mask, x16, n4, xb,
                                      W_pos, W_neg, WT);

    const int waves = (n + NPW - 1) / NPW;            // 3125
    dim3 grid((waves + 3) / 4);                       // 782 blocks x 4 waves
    // layer 0
    fused_layer<<<grid, 256, 0, stream>>>(x16, adj, weight, mask,
                                          WT + 0 * DD * DD, WT + 1 * DD * DD,
                                          nullptr, y16, n, 1);
    // layer 1
    fused_layer<<<grid, 256, 0, stream>>>(y16, adj, weight, mask,
                                          WT + 2 * DD * DD, WT + 3 * DD * DD,
                                          (float*)d_out, nullptr, n, 0);
}

// Round 10
// 194.096 us; speedup vs baseline: 1.2177x; 1.0302x over previous
//
#include <hip/hip_runtime.h>
#include <math.h>

#define DD 128          // embed dim
#define DEG 16          // neighbors
#define TM 16           // node tile per block (grid = 50000/16 = 3125)
#define LDST 136        // LDS row stride in f16
#define EPSV 1e-5f

typedef _Float16 half4_t __attribute__((ext_vector_type(4)));
typedef _Float16 half8_t __attribute__((ext_vector_type(8)));
typedef float    f32x4   __attribute__((ext_vector_type(4)));

// ---- prep (single kernel): x16[s] = x[s]*mask[s]^2 (f16), plus W->f16 transpose.
// Folding mask^2 removes all mask gathers: msg[s] = m_s*((m_s*x[s])@W) = (m_s^2*x[s])@W.
__global__ void prep(const float* __restrict__ x, const float* __restrict__ mask,
                     _Float16* __restrict__ x16, int n4, int xb,
                     const float* __restrict__ Wp, const float* __restrict__ Wn,
                     _Float16* __restrict__ WT)
{
    if ((int)blockIdx.x < xb) {
        int i = blockIdx.x * blockDim.x + threadIdx.x;
        if (i >= n4) return;
        float m = mask[i >> 5];            // 32 half4 groups per row
        float m2 = m * m;
        float4 v = ((const float4*)x)[i];
        half4_t h;
        h[0] = (_Float16)(v.x * m2); h[1] = (_Float16)(v.y * m2);
        h[2] = (_Float16)(v.z * m2); h[3] = (_Float16)(v.w * m2);
        ((half4_t*)x16)[i] = h;
    } else {
        int bid   = blockIdx.x - xb;
        int mat   = bid >> 3;              // 0..3: [l0p, l0n, l1p, l1n]
        int chunk = bid & 7;
        int l = mat >> 1, rel = mat & 1;
        const float* __restrict__ src = (rel ? Wn : Wp) + (size_t)l * DD * DD;
        _Float16* __restrict__ dst = WT + (size_t)mat * DD * DD;
        for (int o = chunk * 2048 + threadIdx.x; o < chunk * 2048 + 2048; o += 256) {
            int nn = o >> 7, kk = o & 127;
            dst[o] = (_Float16)src[kk * DD + nn];   // WT[n][k] (transposed)
        }
    }
}

// ---- one fused GNN layer; EDGE-SPLIT gather: wave w handles edges [4w,4w+4)
//      of all 16 nodes -> 4 partial agg slices, summed at MFMA fragment load ----
__global__ __launch_bounds__(256, 4) void fused_layer(
    const _Float16* __restrict__ src16,          // pre-scaled by mask^2
    const int*   __restrict__ adj, const float* __restrict__ wgt,
    const float* __restrict__ mask,
    const _Float16* __restrict__ WTp, const _Float16* __restrict__ WTn,
    float* __restrict__ dst_f32, _Float16* __restrict__ dst_f16,
    int n, int apply_logmap)
{
    __shared__ __align__(16) _Float16 aggP[4][TM][LDST];   // 17.4 KB (4 partials)
    __shared__ __align__(16) _Float16 aggN[4][TM][LDST];   // 17.4 KB
    __shared__ float partA[4][TM];                          // cross-wave norm partials
    __shared__ float partB[4][TM];

    const int row0   = blockIdx.x * TM;
    const int tid    = threadIdx.x;
    const int wv     = tid >> 6;       // wave 0..3: owns edge slice [4wv, 4wv+4)
    const int l64    = tid & 63;
    const int hw     = l64 >> 5;       // half-wave 0/1 -> node strip of 8
    const int lane32 = l64 & 31;       // covers cols [4*lane32, 4*lane32+4)

    // ---- phase 1 metadata: lane l covers node (l>>2), edge 4wv+(l&3) of strip ----
    const int hrow0 = row0 + hw * 8;
    const int mnode = hrow0 + (lane32 >> 2);
    const int moff  = (mnode < n ? mnode : 0) * DEG + 4 * wv + (lane32 & 3);
    int   mi = adj[moff];
    float mw = wgt[moff];

    // ---- issue ALL 32 gathers of this wave's strip (8 nodes x 4 edges) ----
    half4_t v[32];
    #pragma unroll
    for (int i = 0; i < 8; ++i) {
        #pragma unroll
        for (int j = 0; j < 4; ++j) {
            int idx = __shfl(mi, 4 * i + j, 32);
            v[4 * i + j] = *(const half4_t*)(src16 + (size_t)idx * DD + lane32 * 4);
        }
    }
    // ---- accumulate per node, write this wave's partial slice ----
    #pragma unroll
    for (int i = 0; i < 8; ++i) {
        float aP[4] = {0.f, 0.f, 0.f, 0.f};
        float aN[4] = {0.f, 0.f, 0.f, 0.f};
        #pragma unroll
        for (int j = 0; j < 4; ++j) {
            float w  = __shfl(mw, 4 * i + j, 32);
            float wp = fmaxf(w, 0.f);
            float wn = fmaxf(-w, 0.f);
            #pragma unroll
            for (int c = 0; c < 4; ++c) {
                float f = (float)v[4 * i + j][c];
                aP[c] += wp * f;
                aN[c] += wn * f;
            }
        }
        half4_t hP, hN;
        #pragma unroll
        for (int c = 0; c < 4; ++c) { hP[c] = (_Float16)aP[c]; hN[c] = (_Float16)aN[c]; }
        const int r = hw * 8 + i;
        *(half4_t*)&aggP[wv][r][lane32 * 4] = hP;
        *(half4_t*)&aggN[wv][r][lane32 * 4] = hN;
    }
    __syncthreads();

    // ---- phase 2: MFMA; fragments = sum of the 4 partial slices.
    //      4 waves split the 8 n-blocks (2 each); rows shared ----
    const int l15  = l64 & 15;
    const int quad = l64 >> 4;

    half8_t aPf[4], aNf[4];          // A[m=l15][k=kb*32+quad*8+j]
    #pragma unroll
    for (int kb = 0; kb < 4; ++kb) {
        const int o = kb * 32 + quad * 8;
        half8_t p = *(const half8_t*)&aggP[0][l15][o];
        half8_t q = *(const half8_t*)&aggN[0][l15][o];
        #pragma unroll
        for (int w = 1; w < 4; ++w) {
            p = p + *(const half8_t*)&aggP[w][l15][o];
            q = q + *(const half8_t*)&aggN[w][l15][o];
        }
        aPf[kb] = p; aNf[kb] = q;
    }

    f32x4 acc[2];
    acc[0] = (f32x4){0.f, 0.f, 0.f, 0.f};
    acc[1] = (f32x4){0.f, 0.f, 0.f, 0.f};
    #pragma unroll
    for (int t = 0; t < 2; ++t) {
        const int nb = wv * 2 + t;
        const _Float16* bp = WTp + (size_t)(nb * 16 + l15) * DD + quad * 8;
        const _Float16* bn = WTn + (size_t)(nb * 16 + l15) * DD + quad * 8;
        #pragma unroll
        for (int kb = 0; kb < 4; ++kb) {
            acc[t] = __builtin_amdgcn_mfma_f32_16x16x32_f16(
                aPf[kb], *(const half8_t*)(bp + kb * 32), acc[t], 0, 0, 0);
            acc[t] = __builtin_amdgcn_mfma_f32_16x16x32_f16(
                aNf[kb], *(const half8_t*)(bn + kb * 32), acc[t], 0, 0, 0);
        }
    }

    // ---- phase 3: epilogue. C/D: row=quad*4+r, cols wv*32 + {l15, 16+l15} ----
    float cv0[4], cv1[4], mr[4];
    #pragma unroll
    for (int r = 0; r < 4; ++r) {
        const int rl  = quad * 4 + r;
        const int row = row0 + rl;
        float m = (row < n) ? mask[row] : 0.f;
        mr[r] = m;
        float c0 = acc[0][r] * m, c1 = acc[1][r] * m;
        cv0[r] = c0; cv1[r] = c1;
        float p = c0 * c0 + c1 * c1;
        p += __shfl_xor(p, 1); p += __shfl_xor(p, 2);
        p += __shfl_xor(p, 4); p += __shfl_xor(p, 8);   // within 16-lane group
        if (l15 == 0) partA[wv][rl] = p;
    }
    __syncthreads();

    float x0[4], x1[4];
    #pragma unroll
    for (int r = 0; r < 4; ++r) {
        const int rl = quad * 4 + r;
        float c2 = partA[0][rl] + partA[1][rl] + partA[2][rl] + partA[3][rl];
        float nc = fmaxf(sqrtf(c2), EPSV);
        float sc = tanhf(nc) / nc;
        float m  = mr[r];
        float t0 = fmaxf(cv0[r] * sc * m, 0.f) * m;      // expmap*m, relu, *m
        float t1 = fmaxf(cv1[r] * sc * m, 0.f) * m;
        x0[r] = t0; x1[r] = t1;
        if (apply_logmap) {                               // uniform branch
            float p = t0 * t0 + t1 * t1;
            p += __shfl_xor(p, 1); p += __shfl_xor(p, 2);
            p += __shfl_xor(p, 4); p += __shfl_xor(p, 8);
            if (l15 == 0) partB[wv][rl] = p;
        }
    }

    if (apply_logmap) {
        __syncthreads();
        #pragma unroll
        for (int r = 0; r < 4; ++r) {
            const int rl  = quad * 4 + r;
            const int row = row0 + rl;
            if (row >= n) continue;
            float s2  = partB[0][rl] + partB[1][rl] + partB[2][rl] + partB[3][rl];
            float nc2 = fminf(fmaxf(sqrtf(s2), EPSV), 1.f - EPSV);
            // store logmap(x)*mask^2 so the next layer's gather needs no mask
            float f = (atanhf(nc2) / nc2) * mr[r] * mr[r];
            _Float16* drow = dst_f16 + (size_t)row * DD + wv * 32 + l15;
            drow[0]  = (_Float16)(x0[r] * f);
            drow[16] = (_Float16)(x1[r] * f);
        }
    } else {
        #pragma unroll
        for (int r = 0; r < 4; ++r) {
            const int rl  = quad * 4 + r;
            const int row = row0 + rl;
            if (row >= n) continue;
            float* drow = dst_f32 + (size_t)row * DD + wv * 32 + l15;
            drow[0]  = x0[r];
            drow[16] = x1[r];
        }
    }
}

extern "C" void kernel_launch(void* const* d_in, const int* in_sizes, int n_in,
                              void* d_out, int out_size, void* d_ws, size_t ws_size,
                              hipStream_t stream)
{
    const float* node_repr = (const float*)d_in[0];
    const int*   adj       = (const int*)  d_in[1];
    const float* weight    = (const float*)d_in[2];
    const float* mask      = (const float*)d_in[3];
    const float* W_pos     = (const float*)d_in[4];   // [L,128,128]
    const float* W_neg     = (const float*)d_in[5];

    const int n = in_sizes[0] / DD;                   // 50000

    _Float16* x16 = (_Float16*)d_ws;                  // n*128 f16
    _Float16* y16 = x16 + (size_t)n * DD;             // n*128 f16
    _Float16* WT  = y16 + (size_t)n * DD;             // 4 * 128*128 f16

    const int n4 = n * DD / 4;
    const int xb = (n4 + 255) / 256;
    prep<<<xb + 32, 256, 0, stream>>>(node_repr, mask, x16, n4, xb,
                                      W_pos, W_neg, WT);

    dim3 grid((n + TM - 1) / TM);                     // 3125 blocks x 4 waves
    // layer 0
    fused_layer<<<grid, 256, 0, stream>>>(x16, adj, weight, mask,
                                          WT + 0 * DD * DD, WT + 1 * DD * DD,
                                          nullptr, y16, n, 1);
    // layer 1
    fused_layer<<<grid, 256, 0, stream>>>(y16, adj, weight, mask,
                                          WT + 2 * DD * DD, WT + 3 * DD * DD,
                                          (float*)d_out, nullptr, n, 0);
}